// Round 1
// baseline (384.433 us; speedup 1.0000x reference)
//
#include <hip/hip_runtime.h>

#define BATCH 8192
#define DIM   512

typedef __attribute__((ext_vector_type(8))) short short8;
typedef __attribute__((ext_vector_type(4))) float f32x4;
typedef unsigned short ushort_t;

// round-to-nearest-even f32 -> bf16 (bit pattern)
__device__ __forceinline__ ushort_t f2bf(float f){
  unsigned u = __float_as_uint(f);
  unsigned r = (u + 0x7FFFu + ((u >> 16) & 1u)) >> 16;
  return (ushort_t)r;
}

// --- Kernel 1: L2-normalize rows, emit bf16 hi/lo split ---------------------
__global__ __launch_bounds__(256) void k_normalize(const float* __restrict__ x,
                                                   ushort_t* __restrict__ hi,
                                                   ushort_t* __restrict__ lo){
  const int row  = blockIdx.x * 4 + (threadIdx.x >> 6);
  const int lane = threadIdx.x & 63;
  const float* xr = x + (size_t)row * DIM + lane * 8;
  float4 a = *(const float4*)xr;
  float4 b = *(const float4*)(xr + 4);
  float s = a.x*a.x + a.y*a.y + a.z*a.z + a.w*a.w
          + b.x*b.x + b.y*b.y + b.z*b.z + b.w*b.w;
  #pragma unroll
  for (int m = 1; m < 64; m <<= 1) s += __shfl_xor(s, m);
  const float inv = 1.0f / fmaxf(sqrtf(s), 1e-12f);
  float f[8] = {a.x, a.y, a.z, a.w, b.x, b.y, b.z, b.w};
  ushort_t h[8], l[8];
  #pragma unroll
  for (int e = 0; e < 8; e++){
    float v  = f[e] * inv;
    ushort_t hb = f2bf(v);
    float hf = __uint_as_float(((unsigned)hb) << 16);
    h[e] = hb;
    l[e] = f2bf(v - hf);
  }
  size_t off = (size_t)row * DIM + lane * 8;
  *(short8*)(hi + off) = *(const short8*)h;
  *(short8*)(lo + off) = *(const short8*)l;
}

// --- Kernel 2: upper-triangle tiled f*f^T with fused exp/mask/reduce --------
// 128x128 tile per block, 4 waves (2x2), each wave 64x64 = 4x4 frags of 16x16.
// sim = hi*hi^T + hi*lo^T + lo*hi^T  (3 bf16 MFMAs per k-step).
// Partial sums land in ppos/ptot[c2][row], c2 = column half-tile index
// (2*bj+wc for rowsums, 2*bi+wr for colsums) -> each slot written exactly once
// => fully deterministic, no atomics.
__global__ __launch_bounds__(256) void k_gemm(const ushort_t* __restrict__ hi,
                                              const ushort_t* __restrict__ lo,
                                              const int* __restrict__ labels,
                                              float* __restrict__ ppos,
                                              float* __restrict__ ptot){
  const int bj = blockIdx.x, bi = blockIdx.y;
  if (bi > bj) return;

  __shared__ int labI[128], labJ[128];
  if (threadIdx.x < 128) labI[threadIdx.x] = labels[bi * 128 + threadIdx.x];
  else                   labJ[threadIdx.x - 128] = labels[bj * 128 + (threadIdx.x - 128)];
  __syncthreads();

  const int lane = threadIdx.x & 63;
  const int w  = threadIdx.x >> 6;
  const int wr = w >> 1, wc = w & 1;
  const int i0 = bi * 128 + wr * 64;
  const int j0 = bj * 128 + wc * 64;
  const int lrow = lane & 15;
  const int g    = lane >> 4;
  const int kgrp = g * 8;

  f32x4 acc[4][4];
  #pragma unroll
  for (int m = 0; m < 4; m++)
    #pragma unroll
    for (int n = 0; n < 4; n++)
      acc[m][n] = (f32x4){0.f, 0.f, 0.f, 0.f};

  for (int kk = 0; kk < DIM; kk += 32){
    short8 ah[4], al[4], bh[4], bl[4];
    #pragma unroll
    for (int m = 0; m < 4; m++){
      size_t o = (size_t)(i0 + m * 16 + lrow) * DIM + kk + kgrp;
      ah[m] = *(const short8*)(hi + o);
      al[m] = *(const short8*)(lo + o);
    }
    #pragma unroll
    for (int n = 0; n < 4; n++){
      size_t o = (size_t)(j0 + n * 16 + lrow) * DIM + kk + kgrp;
      bh[n] = *(const short8*)(hi + o);
      bl[n] = *(const short8*)(lo + o);
    }
    #pragma unroll
    for (int m = 0; m < 4; m++)
      #pragma unroll
      for (int n = 0; n < 4; n++){
        acc[m][n] = __builtin_amdgcn_mfma_f32_16x16x32_bf16(ah[m], bh[n], acc[m][n], 0, 0, 0);
        acc[m][n] = __builtin_amdgcn_mfma_f32_16x16x32_bf16(ah[m], bl[n], acc[m][n], 0, 0, 0);
        acc[m][n] = __builtin_amdgcn_mfma_f32_16x16x32_bf16(al[m], bh[n], acc[m][n], 0, 0, 0);
      }
  }

  // labels into registers
  int li_[4][4], lj_[4];
  #pragma unroll
  for (int m = 0; m < 4; m++)
    #pragma unroll
    for (int e = 0; e < 4; e++)
      li_[m][e] = labI[wr * 64 + m * 16 + g * 4 + e];
  #pragma unroll
  for (int n = 0; n < 4; n++)
    lj_[n] = labJ[wc * 64 + n * 16 + lrow];

  // exp + diag mask, in place
  const float invT = 14.285714285714286f;  // 1/0.07
  #pragma unroll
  for (int m = 0; m < 4; m++)
    #pragma unroll
    for (int n = 0; n < 4; n++)
      #pragma unroll
      for (int e = 0; e < 4; e++){
        int i = i0 + m * 16 + g * 4 + e;
        int j = j0 + n * 16 + lrow;
        float v = (i == j) ? 0.0f : __expf(acc[m][n][e] * invT);
        acc[m][n][e] = v;
      }

  // row sums (rows of bi block) -> slot c2 = 2*bj + wc
  {
    float* pp = ppos + (size_t)(2 * bj + wc) * BATCH;
    float* pt = ptot + (size_t)(2 * bj + wc) * BATCH;
    #pragma unroll
    for (int m = 0; m < 4; m++){
      float tr[4] = {0, 0, 0, 0}, pr[4] = {0, 0, 0, 0};
      #pragma unroll
      for (int n = 0; n < 4; n++){
        int lj = lj_[n];
        #pragma unroll
        for (int e = 0; e < 4; e++){
          float v = acc[m][n][e];
          tr[e] += v;
          pr[e] += (li_[m][e] == lj) ? v : 0.0f;
        }
      }
      #pragma unroll
      for (int s = 1; s < 16; s <<= 1){
        #pragma unroll
        for (int e = 0; e < 4; e++){
          tr[e] += __shfl_xor(tr[e], s);
          pr[e] += __shfl_xor(pr[e], s);
        }
      }
      if (lrow == 0){
        int ib = i0 + m * 16 + g * 4;
        #pragma unroll
        for (int e = 0; e < 4; e++){
          pt[ib + e] = tr[e];
          pp[ib + e] = pr[e];
        }
      }
    }
  }

  // col sums (rows of bj block, via symmetry) -> slot c2 = 2*bi + wr
  if (bi != bj){
    float* pp = ppos + (size_t)(2 * bi + wr) * BATCH;
    float* pt = ptot + (size_t)(2 * bi + wr) * BATCH;
    #pragma unroll
    for (int n = 0; n < 4; n++){
      float ts = 0.f, ps = 0.f;
      int lj = lj_[n];
      #pragma unroll
      for (int m = 0; m < 4; m++)
        #pragma unroll
        for (int e = 0; e < 4; e++){
          float v = acc[m][n][e];
          ts += v;
          ps += (li_[m][e] == lj) ? v : 0.0f;
        }
      ts += __shfl_xor(ts, 16); ps += __shfl_xor(ps, 16);
      ts += __shfl_xor(ts, 32); ps += __shfl_xor(ps, 32);
      if (lane < 16){
        int j = j0 + n * 16 + lane;
        pt[j] = ts;
        pp[j] = ps;
      }
    }
  }
}

// --- Kernel 3: per-row loss, per-block partial sum --------------------------
__global__ __launch_bounds__(256) void k_rowloss(const float* __restrict__ ppos,
                                                 const float* __restrict__ ptot,
                                                 float* __restrict__ bsum){
  const int i = blockIdx.x * 256 + threadIdx.x;
  float p = 0.f, t = 0.f;
  for (int c = 0; c < 128; c++){
    p += ppos[(size_t)c * BATCH + i];
    t += ptot[(size_t)c * BATCH + i];
  }
  float loss = -logf(p / (t + 1e-8f));
  float v = loss;
  #pragma unroll
  for (int s = 1; s < 64; s <<= 1) v += __shfl_xor(v, s);
  __shared__ float ws4[4];
  if ((threadIdx.x & 63) == 0) ws4[threadIdx.x >> 6] = v;
  __syncthreads();
  if (threadIdx.x == 0) bsum[blockIdx.x] = ws4[0] + ws4[1] + ws4[2] + ws4[3];
}

// --- Kernel 4: final mean ---------------------------------------------------
__global__ __launch_bounds__(64) void k_final(const float* __restrict__ bsum,
                                              float* __restrict__ out){
  float v = (threadIdx.x < 32) ? bsum[threadIdx.x] : 0.f;
  #pragma unroll
  for (int s = 1; s < 64; s <<= 1) v += __shfl_xor(v, s);
  if (threadIdx.x == 0) out[0] = v * (1.0f / 8192.0f);
}

extern "C" void kernel_launch(void* const* d_in, const int* in_sizes, int n_in,
                              void* d_out, int out_size, void* d_ws, size_t ws_size,
                              hipStream_t stream){
  const float* x      = (const float*)d_in[0];
  const int*   labels = (const int*)d_in[1];
  float*       out    = (float*)d_out;

  char* ws = (char*)d_ws;
  ushort_t* hi  = (ushort_t*)ws;                          //  8,388,608 B
  ushort_t* lo  = (ushort_t*)(ws + 8388608);              //  8,388,608 B
  float* ppos   = (float*)(ws + 16777216);                //  4,194,304 B (128 x 8192 f32)
  float* ptot   = (float*)(ws + 16777216 + 4194304);      //  4,194,304 B
  float* bsum   = (float*)(ws + 16777216 + 8388608);      //        128 B

  k_normalize<<<BATCH / 4, 256, 0, stream>>>(x, hi, lo);
  k_gemm<<<dim3(64, 64), 256, 0, stream>>>(hi, lo, labels, ppos, ptot);
  k_rowloss<<<BATCH / 256, 256, 0, stream>>>(ppos, ptot, bsum);
  k_final<<<1, 64, 0, stream>>>(bsum, out);
}

// Round 2
// 162.986 us; speedup vs baseline: 2.3587x; 2.3587x over previous
//
#include <hip/hip_runtime.h>

#define BATCH 8192
#define DIM   512
#define BK    32
#define NTILE 64                       // 8192 / 128
#define NBLK  (NTILE*(NTILE+1)/2)      // 2080 upper-triangle tiles

typedef __attribute__((ext_vector_type(8))) short short8;
typedef __attribute__((ext_vector_type(4))) float f32x4;
typedef unsigned short ushort_t;

// round-to-nearest-even f32 -> bf16 (bit pattern)
__device__ __forceinline__ ushort_t f2bf(float f){
  unsigned u = __float_as_uint(f);
  unsigned r = (u + 0x7FFFu + ((u >> 16) & 1u)) >> 16;
  return (ushort_t)r;
}

// async global->LDS, 16B per lane; LDS dest = wave-uniform base + lane*16
__device__ __forceinline__ void gload_lds16(const ushort_t* g, ushort_t* l){
  __builtin_amdgcn_global_load_lds(
      (const __attribute__((address_space(1))) void*)g,
      (__attribute__((address_space(3))) void*)l, 16, 0, 0);
}

// --- Kernel 1: L2-normalize rows, emit bf16 hi/lo split ---------------------
__global__ __launch_bounds__(256) void k_normalize(const float* __restrict__ x,
                                                   ushort_t* __restrict__ hi,
                                                   ushort_t* __restrict__ lo){
  const int row  = blockIdx.x * 4 + (threadIdx.x >> 6);
  const int lane = threadIdx.x & 63;
  const float* xr = x + (size_t)row * DIM + lane * 8;
  float4 a = *(const float4*)xr;
  float4 b = *(const float4*)(xr + 4);
  float s = a.x*a.x + a.y*a.y + a.z*a.z + a.w*a.w
          + b.x*b.x + b.y*b.y + b.z*b.z + b.w*b.w;
  #pragma unroll
  for (int m = 1; m < 64; m <<= 1) s += __shfl_xor(s, m);
  const float inv = 1.0f / fmaxf(sqrtf(s), 1e-12f);
  float f[8] = {a.x, a.y, a.z, a.w, b.x, b.y, b.z, b.w};
  ushort_t h[8], l[8];
  #pragma unroll
  for (int e = 0; e < 8; e++){
    float v  = f[e] * inv;
    ushort_t hb = f2bf(v);
    float hf = __uint_as_float(((unsigned)hb) << 16);
    h[e] = hb;
    l[e] = f2bf(v - hf);
  }
  size_t off = (size_t)row * DIM + lane * 8;
  *(short8*)(hi + off) = *(const short8*)h;
  *(short8*)(lo + off) = *(const short8*)l;
}

// --- Kernel 2: upper-triangle tiled f*f^T, m97-style LDS staging ------------
// 128x128 tile, 4 waves (2x2), each wave 64x64 = 4x4 frags of 16x16x32.
// Per k-step: stage Ahi/Alo/Bhi/Blo [128][32] bf16 via global_load_lds(16B),
// then ds_read_b128 frags, then 3 passes of 16 MFMAs (hh, hl, lh) so the
// dependent-accumulate distance is 16 MFMAs.
__global__ __launch_bounds__(256) void k_gemm(const ushort_t* __restrict__ hi,
                                              const ushort_t* __restrict__ lo,
                                              const int* __restrict__ labels,
                                              float* __restrict__ ppos,
                                              float* __restrict__ ptot){
  // triangular decode: bid -> (bi <= bj)
  const int bid = blockIdx.x;
  int bj = (int)((sqrtf(8.0f * (float)bid + 1.0f) - 1.0f) * 0.5f);
  while ((bj + 1) * (bj + 2) / 2 <= bid) bj++;
  while (bj * (bj + 1) / 2 > bid) bj--;
  const int bi = bid - bj * (bj + 1) / 2;

  __shared__ ushort_t sAh[128 * BK], sAl[128 * BK];
  __shared__ ushort_t sBh[128 * BK], sBl[128 * BK];
  __shared__ int labI[128], labJ[128];
  if (threadIdx.x < 128) labI[threadIdx.x] = labels[bi * 128 + threadIdx.x];
  else                   labJ[threadIdx.x - 128] = labels[bj * 128 + (threadIdx.x - 128)];

  const int t    = threadIdx.x;
  const int lane = t & 63;
  const int w    = t >> 6;
  const int wr   = w >> 1, wc = w & 1;
  const int lrow = lane & 15;
  const int g    = lane >> 4;

  // staging geometry: array [128][32] bf16 = 8192B; thread t owns bytes
  // t*16 (half 0) and 4096 + t*16 (half 1). row = o/64, col-elem = (o%64)/2.
  const int r0 = (t * 16) >> 6;          // 0..63
  const int c0 = ((t * 16) & 63) >> 1;   // 0,8,16,24
  const size_t gA0 = (size_t)(bi * 128 +      r0) * DIM + c0;
  const size_t gA1 = (size_t)(bi * 128 + 64 + r0) * DIM + c0;
  const size_t gB0 = (size_t)(bj * 128 +      r0) * DIM + c0;
  const size_t gB1 = (size_t)(bj * 128 + 64 + r0) * DIM + c0;
  const int d0 = w * 512;                // wave-uniform LDS elem base, half 0
  const int d1 = 2048 + w * 512;         // half 1

  f32x4 acc[4][4];
  #pragma unroll
  for (int m = 0; m < 4; m++)
    #pragma unroll
    for (int n = 0; n < 4; n++)
      acc[m][n] = (f32x4){0.f, 0.f, 0.f, 0.f};

  for (int kk = 0; kk < DIM; kk += BK){
    __syncthreads();                     // prev compute done before overwrite
    gload_lds16(hi + gA0 + kk, sAh + d0);
    gload_lds16(hi + gA1 + kk, sAh + d1);
    gload_lds16(lo + gA0 + kk, sAl + d0);
    gload_lds16(lo + gA1 + kk, sAl + d1);
    gload_lds16(hi + gB0 + kk, sBh + d0);
    gload_lds16(hi + gB1 + kk, sBh + d1);
    gload_lds16(lo + gB0 + kk, sBl + d0);
    gload_lds16(lo + gB1 + kk, sBl + d1);
    __syncthreads();                     // drains vmcnt before barrier

    short8 ah[4], al[4], bh[4], bl[4];
    #pragma unroll
    for (int m = 0; m < 4; m++){
      const int ra = (wr * 64 + m * 16 + lrow) * BK + g * 8;
      ah[m] = *(const short8*)(sAh + ra);
      al[m] = *(const short8*)(sAl + ra);
    }
    #pragma unroll
    for (int n = 0; n < 4; n++){
      const int rb = (wc * 64 + n * 16 + lrow) * BK + g * 8;
      bh[n] = *(const short8*)(sBh + rb);
      bl[n] = *(const short8*)(sBl + rb);
    }
    #pragma unroll
    for (int m = 0; m < 4; m++)
      #pragma unroll
      for (int n = 0; n < 4; n++)
        acc[m][n] = __builtin_amdgcn_mfma_f32_16x16x32_bf16(ah[m], bh[n], acc[m][n], 0, 0, 0);
    #pragma unroll
    for (int m = 0; m < 4; m++)
      #pragma unroll
      for (int n = 0; n < 4; n++)
        acc[m][n] = __builtin_amdgcn_mfma_f32_16x16x32_bf16(ah[m], bl[n], acc[m][n], 0, 0, 0);
    #pragma unroll
    for (int m = 0; m < 4; m++)
      #pragma unroll
      for (int n = 0; n < 4; n++)
        acc[m][n] = __builtin_amdgcn_mfma_f32_16x16x32_bf16(al[m], bh[n], acc[m][n], 0, 0, 0);
  }

  const int i0 = bi * 128 + wr * 64;
  const int j0 = bj * 128 + wc * 64;

  // labels into registers
  int li_[4][4], lj_[4];
  #pragma unroll
  for (int m = 0; m < 4; m++)
    #pragma unroll
    for (int e = 0; e < 4; e++)
      li_[m][e] = labI[wr * 64 + m * 16 + g * 4 + e];
  #pragma unroll
  for (int n = 0; n < 4; n++)
    lj_[n] = labJ[wc * 64 + n * 16 + lrow];

  // exp + diag mask, in place
  const float invT = 14.285714285714286f;  // 1/0.07
  #pragma unroll
  for (int m = 0; m < 4; m++)
    #pragma unroll
    for (int n = 0; n < 4; n++)
      #pragma unroll
      for (int e = 0; e < 4; e++){
        int i = i0 + m * 16 + g * 4 + e;
        int j = j0 + n * 16 + lrow;
        float v = (i == j) ? 0.0f : __expf(acc[m][n][e] * invT);
        acc[m][n][e] = v;
      }

  // row sums (rows of bi block) -> slot c2 = 2*bj + wc
  {
    float* pp = ppos + (size_t)(2 * bj + wc) * BATCH;
    float* pt = ptot + (size_t)(2 * bj + wc) * BATCH;
    #pragma unroll
    for (int m = 0; m < 4; m++){
      float tr[4] = {0, 0, 0, 0}, pr[4] = {0, 0, 0, 0};
      #pragma unroll
      for (int n = 0; n < 4; n++){
        int lj = lj_[n];
        #pragma unroll
        for (int e = 0; e < 4; e++){
          float v = acc[m][n][e];
          tr[e] += v;
          pr[e] += (li_[m][e] == lj) ? v : 0.0f;
        }
      }
      #pragma unroll
      for (int s = 1; s < 16; s <<= 1){
        #pragma unroll
        for (int e = 0; e < 4; e++){
          tr[e] += __shfl_xor(tr[e], s);
          pr[e] += __shfl_xor(pr[e], s);
        }
      }
      if (lrow == 0){
        int ib = i0 + m * 16 + g * 4;
        #pragma unroll
        for (int e = 0; e < 4; e++){
          pt[ib + e] = tr[e];
          pp[ib + e] = pr[e];
        }
      }
    }
  }

  // col sums (rows of bj block, via symmetry) -> slot c2 = 2*bi + wr
  if (bi != bj){
    float* pp = ppos + (size_t)(2 * bi + wr) * BATCH;
    float* pt = ptot + (size_t)(2 * bi + wr) * BATCH;
    #pragma unroll
    for (int n = 0; n < 4; n++){
      float ts = 0.f, ps = 0.f;
      int lj = lj_[n];
      #pragma unroll
      for (int m = 0; m < 4; m++)
        #pragma unroll
        for (int e = 0; e < 4; e++){
          float v = acc[m][n][e];
          ts += v;
          ps += (li_[m][e] == lj) ? v : 0.0f;
        }
      ts += __shfl_xor(ts, 16); ps += __shfl_xor(ps, 16);
      ts += __shfl_xor(ts, 32); ps += __shfl_xor(ps, 32);
      if (lane < 16){
        int j = j0 + n * 16 + lane;
        pt[j] = ts;
        pp[j] = ps;
      }
    }
  }
}

// --- Kernel 3: per-row loss, per-block partial sum --------------------------
__global__ __launch_bounds__(256) void k_rowloss(const float* __restrict__ ppos,
                                                 const float* __restrict__ ptot,
                                                 float* __restrict__ bsum){
  const int i = blockIdx.x * 256 + threadIdx.x;
  float p = 0.f, t = 0.f;
  for (int c = 0; c < 128; c++){
    p += ppos[(size_t)c * BATCH + i];
    t += ptot[(size_t)c * BATCH + i];
  }
  float loss = -logf(p / (t + 1e-8f));
  float v = loss;
  #pragma unroll
  for (int s = 1; s < 64; s <<= 1) v += __shfl_xor(v, s);
  __shared__ float ws4[4];
  if ((threadIdx.x & 63) == 0) ws4[threadIdx.x >> 6] = v;
  __syncthreads();
  if (threadIdx.x == 0) bsum[blockIdx.x] = ws4[0] + ws4[1] + ws4[2] + ws4[3];
}

// --- Kernel 4: final mean ---------------------------------------------------
__global__ __launch_bounds__(64) void k_final(const float* __restrict__ bsum,
                                              float* __restrict__ out){
  float v = (threadIdx.x < 32) ? bsum[threadIdx.x] : 0.f;
  #pragma unroll
  for (int s = 1; s < 64; s <<= 1) v += __shfl_xor(v, s);
  if (threadIdx.x == 0) out[0] = v * (1.0f / 8192.0f);
}

extern "C" void kernel_launch(void* const* d_in, const int* in_sizes, int n_in,
                              void* d_out, int out_size, void* d_ws, size_t ws_size,
                              hipStream_t stream){
  const float* x      = (const float*)d_in[0];
  const int*   labels = (const int*)d_in[1];
  float*       out    = (float*)d_out;

  char* ws = (char*)d_ws;
  ushort_t* hi  = (ushort_t*)ws;                          //  8,388,608 B
  ushort_t* lo  = (ushort_t*)(ws + 8388608);              //  8,388,608 B
  float* ppos   = (float*)(ws + 16777216);                //  4,194,304 B (128 x 8192 f32)
  float* ptot   = (float*)(ws + 16777216 + 4194304);      //  4,194,304 B
  float* bsum   = (float*)(ws + 16777216 + 8388608);      //        128 B

  k_normalize<<<BATCH / 4, 256, 0, stream>>>(x, hi, lo);
  k_gemm<<<NBLK, 256, 0, stream>>>(hi, lo, labels, ppos, ptot);
  k_rowloss<<<BATCH / 256, 256, 0, stream>>>(ppos, ptot, bsum);
  k_final<<<1, 64, 0, stream>>>(bsum, out);
}

// Round 3
// 150.345 us; speedup vs baseline: 2.5570x; 1.0841x over previous
//
#include <hip/hip_runtime.h>

#define BATCH 8192
#define DIM   512
#define BK    32
#define NTILE 64                       // 8192 / 128
#define NBLK  (NTILE*(NTILE+1)/2)      // 2080 upper-triangle tiles

typedef __attribute__((ext_vector_type(8))) short short8;
typedef __attribute__((ext_vector_type(4))) float f32x4;
typedef unsigned short ushort_t;

// round-to-nearest-even f32 -> bf16 (bit pattern)
__device__ __forceinline__ ushort_t f2bf(float f){
  unsigned u = __float_as_uint(f);
  unsigned r = (u + 0x7FFFu + ((u >> 16) & 1u)) >> 16;
  return (ushort_t)r;
}

// async global->LDS, 16B per lane; LDS dest = wave-uniform base + lane*16
__device__ __forceinline__ void gload_lds16(const ushort_t* g, ushort_t* l){
  __builtin_amdgcn_global_load_lds(
      (const __attribute__((address_space(1))) void*)g,
      (__attribute__((address_space(3))) void*)l, 16, 0, 0);
}

// --- Kernel 1: L2-normalize rows, emit bf16 hi/lo split, SWIZZLED layout ----
// Within each row's 64B k-group (32 bf16), 16B chunk c is stored at position
// c ^ ((row>>1)&3). k_gemm stages linearly (global_load_lds) and applies the
// same XOR on ds_read -> conflict-free LDS reads (involution, rule #21).
__global__ __launch_bounds__(256) void k_normalize(const float* __restrict__ x,
                                                   ushort_t* __restrict__ hi,
                                                   ushort_t* __restrict__ lo){
  const int row  = blockIdx.x * 4 + (threadIdx.x >> 6);
  const int lane = threadIdx.x & 63;
  const float* xr = x + (size_t)row * DIM + lane * 8;
  float4 a = *(const float4*)xr;
  float4 b = *(const float4*)(xr + 4);
  float s = a.x*a.x + a.y*a.y + a.z*a.z + a.w*a.w
          + b.x*b.x + b.y*b.y + b.z*b.z + b.w*b.w;
  #pragma unroll
  for (int m = 1; m < 64; m <<= 1) s += __shfl_xor(s, m);
  const float inv = 1.0f / fmaxf(sqrtf(s), 1e-12f);
  float f[8] = {a.x, a.y, a.z, a.w, b.x, b.y, b.z, b.w};
  ushort_t h[8], l[8];
  #pragma unroll
  for (int e = 0; e < 8; e++){
    float v  = f[e] * inv;
    ushort_t hb = f2bf(v);
    float hf = __uint_as_float(((unsigned)hb) << 16);
    h[e] = hb;
    l[e] = f2bf(v - hf);
  }
  const int grp = lane >> 2;                 // 32-elem k-group (0..15)
  const int ch  = lane & 3;                  // 16B chunk within group
  const int sw  = (row >> 1) & 3;
  size_t off = (size_t)row * DIM + grp * 32 + (size_t)(ch ^ sw) * 8;
  *(short8*)(hi + off) = *(const short8*)h;
  *(short8*)(lo + off) = *(const short8*)l;
}

// --- compute one BK=32 k-step: 16 swizzled ds_read_b128 + 48 MFMA -----------
__device__ __forceinline__ void compute_step(const ushort_t* sAh, const ushort_t* sAl,
                                             const ushort_t* sBh, const ushort_t* sBl,
                                             const int ra[4], const int rb[4],
                                             f32x4 (&acc)[4][4]){
  short8 ah[4], al[4], bh[4], bl[4];
  #pragma unroll
  for (int m = 0; m < 4; m++){
    ah[m] = *(const short8*)(sAh + ra[m]);
    al[m] = *(const short8*)(sAl + ra[m]);
  }
  #pragma unroll
  for (int n = 0; n < 4; n++){
    bh[n] = *(const short8*)(sBh + rb[n]);
    bl[n] = *(const short8*)(sBl + rb[n]);
  }
  #pragma unroll
  for (int m = 0; m < 4; m++)
    #pragma unroll
    for (int n = 0; n < 4; n++)
      acc[m][n] = __builtin_amdgcn_mfma_f32_16x16x32_bf16(ah[m], bh[n], acc[m][n], 0, 0, 0);
  #pragma unroll
  for (int m = 0; m < 4; m++)
    #pragma unroll
    for (int n = 0; n < 4; n++)
      acc[m][n] = __builtin_amdgcn_mfma_f32_16x16x32_bf16(ah[m], bl[n], acc[m][n], 0, 0, 0);
  #pragma unroll
  for (int m = 0; m < 4; m++)
    #pragma unroll
    for (int n = 0; n < 4; n++)
      acc[m][n] = __builtin_amdgcn_mfma_f32_16x16x32_bf16(al[m], bh[n], acc[m][n], 0, 0, 0);
}

// --- Kernel 2: upper-triangle tiled f*f^T, double-buffered overlap ----------
// 128x128 tile, 4 waves (2x2), wave 64x64 = 4x4 frags of 16x16x32.
// Per k-step: issue next tile's global_load_lds FIRST, then ds_read+MFMA on
// the current buffer, then one __syncthreads (= vmcnt(0)+barrier). Staging
// latency hides under ~930 cyc of MFMA.
__global__ __launch_bounds__(256) void k_gemm(const ushort_t* __restrict__ hi,
                                              const ushort_t* __restrict__ lo,
                                              const int* __restrict__ labels,
                                              float* __restrict__ ppos,
                                              float* __restrict__ ptot){
  // triangular decode: bid -> (bi <= bj)
  const int bid = blockIdx.x;
  int bj = (int)((sqrtf(8.0f * (float)bid + 1.0f) - 1.0f) * 0.5f);
  while ((bj + 1) * (bj + 2) / 2 <= bid) bj++;
  while (bj * (bj + 1) / 2 > bid) bj--;
  const int bi = bid - bj * (bj + 1) / 2;

  __shared__ ushort_t sAh0[4096], sAl0[4096], sBh0[4096], sBl0[4096];
  __shared__ ushort_t sAh1[4096], sAl1[4096], sBh1[4096], sBl1[4096];
  __shared__ int labI[128], labJ[128];
  if (threadIdx.x < 128) labI[threadIdx.x] = labels[bi * 128 + threadIdx.x];
  else                   labJ[threadIdx.x - 128] = labels[bj * 128 + (threadIdx.x - 128)];

  const int t    = threadIdx.x;
  const int lane = t & 63;
  const int w    = t >> 6;
  const int wr   = w >> 1, wc = w & 1;
  const int lrow = lane & 15;
  const int g    = lane >> 4;

  // staging geometry: tile [128][32] bf16 = 8192B; identity mapping
  const int r0 = (t * 16) >> 6;          // 0..63
  const int c0 = ((t * 16) & 63) >> 1;   // 0,8,16,24
  const size_t gA0 = (size_t)(bi * 128 +      r0) * DIM + c0;
  const size_t gA1 = (size_t)(bi * 128 + 64 + r0) * DIM + c0;
  const size_t gB0 = (size_t)(bj * 128 +      r0) * DIM + c0;
  const size_t gB1 = (size_t)(bj * 128 + 64 + r0) * DIM + c0;
  const int d0 = w * 512;                // wave-uniform LDS elem base, half 0
  const int d1 = 2048 + w * 512;         // half 1

#define STAGE(SAH, SAL, SBH, SBL, KK) do {            \
    gload_lds16(hi + gA0 + (KK), (SAH) + d0);         \
    gload_lds16(hi + gA1 + (KK), (SAH) + d1);         \
    gload_lds16(lo + gA0 + (KK), (SAL) + d0);         \
    gload_lds16(lo + gA1 + (KK), (SAL) + d1);         \
    gload_lds16(hi + gB0 + (KK), (SBH) + d0);         \
    gload_lds16(hi + gB1 + (KK), (SBH) + d1);         \
    gload_lds16(lo + gB0 + (KK), (SBL) + d0);         \
    gload_lds16(lo + gB1 + (KK), (SBL) + d1);         \
  } while (0)

  // swizzled fragment read offsets (elems): row*32 + ((g ^ ((lrow>>1)&3))*8)
  const int gs = (g ^ ((lrow >> 1) & 3)) * 8;
  int ra[4], rb[4];
  #pragma unroll
  for (int m = 0; m < 4; m++) ra[m] = (wr * 64 + m * 16 + lrow) * 32 + gs;
  #pragma unroll
  for (int n = 0; n < 4; n++) rb[n] = (wc * 64 + n * 16 + lrow) * 32 + gs;

  f32x4 acc[4][4];
  #pragma unroll
  for (int m = 0; m < 4; m++)
    #pragma unroll
    for (int n = 0; n < 4; n++)
      acc[m][n] = (f32x4){0.f, 0.f, 0.f, 0.f};

  STAGE(sAh0, sAl0, sBh0, sBl0, 0);
  __syncthreads();                       // drains prologue DMA + labels

  for (int it = 0; it < 8; it++){
    const int k1 = it * 64;
    STAGE(sAh1, sAl1, sBh1, sBl1, k1 + 32);          // prefetch odd tile
    compute_step(sAh0, sAl0, sBh0, sBl0, ra, rb, acc);
    __syncthreads();                                 // vmcnt(0) + barrier
    if (it < 7) STAGE(sAh0, sAl0, sBh0, sBl0, k1 + 64); // prefetch even tile
    compute_step(sAh1, sAl1, sBh1, sBl1, ra, rb, acc);
    __syncthreads();
  }
#undef STAGE

  const int i0 = bi * 128 + wr * 64;
  const int j0 = bj * 128 + wc * 64;

  // labels into registers
  int li_[4][4], lj_[4];
  #pragma unroll
  for (int m = 0; m < 4; m++)
    #pragma unroll
    for (int e = 0; e < 4; e++)
      li_[m][e] = labI[wr * 64 + m * 16 + g * 4 + e];
  #pragma unroll
  for (int n = 0; n < 4; n++)
    lj_[n] = labJ[wc * 64 + n * 16 + lrow];

  // exp + diag mask, in place
  const float invT = 14.285714285714286f;  // 1/0.07
  #pragma unroll
  for (int m = 0; m < 4; m++)
    #pragma unroll
    for (int n = 0; n < 4; n++)
      #pragma unroll
      for (int e = 0; e < 4; e++){
        int i = i0 + m * 16 + g * 4 + e;
        int j = j0 + n * 16 + lrow;
        float v = (i == j) ? 0.0f : __expf(acc[m][n][e] * invT);
        acc[m][n][e] = v;
      }

  // row sums (rows of bi block) -> slot c2 = 2*bj + wc
  {
    float* pp = ppos + (size_t)(2 * bj + wc) * BATCH;
    float* pt = ptot + (size_t)(2 * bj + wc) * BATCH;
    #pragma unroll
    for (int m = 0; m < 4; m++){
      float tr[4] = {0, 0, 0, 0}, pr[4] = {0, 0, 0, 0};
      #pragma unroll
      for (int n = 0; n < 4; n++){
        int lj = lj_[n];
        #pragma unroll
        for (int e = 0; e < 4; e++){
          float v = acc[m][n][e];
          tr[e] += v;
          pr[e] += (li_[m][e] == lj) ? v : 0.0f;
        }
      }
      #pragma unroll
      for (int s = 1; s < 16; s <<= 1){
        #pragma unroll
        for (int e = 0; e < 4; e++){
          tr[e] += __shfl_xor(tr[e], s);
          pr[e] += __shfl_xor(pr[e], s);
        }
      }
      if (lrow == 0){
        int ib = i0 + m * 16 + g * 4;
        #pragma unroll
        for (int e = 0; e < 4; e++){
          pt[ib + e] = tr[e];
          pp[ib + e] = pr[e];
        }
      }
    }
  }

  // col sums (rows of bj block, via symmetry) -> slot c2 = 2*bi + wr
  if (bi != bj){
    float* pp = ppos + (size_t)(2 * bi + wr) * BATCH;
    float* pt = ptot + (size_t)(2 * bi + wr) * BATCH;
    #pragma unroll
    for (int n = 0; n < 4; n++){
      float ts = 0.f, ps = 0.f;
      int lj = lj_[n];
      #pragma unroll
      for (int m = 0; m < 4; m++)
        #pragma unroll
        for (int e = 0; e < 4; e++){
          float v = acc[m][n][e];
          ts += v;
          ps += (li_[m][e] == lj) ? v : 0.0f;
        }
      ts += __shfl_xor(ts, 16); ps += __shfl_xor(ps, 16);
      ts += __shfl_xor(ts, 32); ps += __shfl_xor(ps, 32);
      if (lane < 16){
        int j = j0 + n * 16 + lane;
        pt[j] = ts;
        pp[j] = ps;
      }
    }
  }
}

// --- Kernel 3: per-row loss, per-block partial sum --------------------------
__global__ __launch_bounds__(256) void k_rowloss(const float* __restrict__ ppos,
                                                 const float* __restrict__ ptot,
                                                 float* __restrict__ bsum){
  const int i = blockIdx.x * 256 + threadIdx.x;
  float p = 0.f, t = 0.f;
  for (int c = 0; c < 128; c++){
    p += ppos[(size_t)c * BATCH + i];
    t += ptot[(size_t)c * BATCH + i];
  }
  float loss = -logf(p / (t + 1e-8f));
  float v = loss;
  #pragma unroll
  for (int s = 1; s < 64; s <<= 1) v += __shfl_xor(v, s);
  __shared__ float ws4[4];
  if ((threadIdx.x & 63) == 0) ws4[threadIdx.x >> 6] = v;
  __syncthreads();
  if (threadIdx.x == 0) bsum[blockIdx.x] = ws4[0] + ws4[1] + ws4[2] + ws4[3];
}

// --- Kernel 4: final mean ---------------------------------------------------
__global__ __launch_bounds__(64) void k_final(const float* __restrict__ bsum,
                                              float* __restrict__ out){
  float v = (threadIdx.x < 32) ? bsum[threadIdx.x] : 0.f;
  #pragma unroll
  for (int s = 1; s < 64; s <<= 1) v += __shfl_xor(v, s);
  if (threadIdx.x == 0) out[0] = v * (1.0f / 8192.0f);
}

extern "C" void kernel_launch(void* const* d_in, const int* in_sizes, int n_in,
                              void* d_out, int out_size, void* d_ws, size_t ws_size,
                              hipStream_t stream){
  const float* x      = (const float*)d_in[0];
  const int*   labels = (const int*)d_in[1];
  float*       out    = (float*)d_out;

  char* ws = (char*)d_ws;
  ushort_t* hi  = (ushort_t*)ws;                          //  8,388,608 B
  ushort_t* lo  = (ushort_t*)(ws + 8388608);              //  8,388,608 B
  float* ppos   = (float*)(ws + 16777216);                //  4,194,304 B (128 x 8192 f32)
  float* ptot   = (float*)(ws + 16777216 + 4194304);      //  4,194,304 B
  float* bsum   = (float*)(ws + 16777216 + 8388608);      //        128 B

  k_normalize<<<BATCH / 4, 256, 0, stream>>>(x, hi, lo);
  k_gemm<<<NBLK, 256, 0, stream>>>(hi, lo, labels, ppos, ptot);
  k_rowloss<<<BATCH / 256, 256, 0, stream>>>(ppos, ptot, bsum);
  k_final<<<1, 64, 0, stream>>>(bsum, out);
}

// Round 4
// 95.446 us; speedup vs baseline: 4.0278x; 1.5752x over previous
//
#include <hip/hip_runtime.h>

#define BATCH 8192
#define DIM   512
#define NSB   32                  // 256-row superblocks
#define NBLK  (NSB * 33)          // 1056 blocks: (I, J) with J in [2I, 64)

typedef __attribute__((ext_vector_type(8))) _Float16 half8;
typedef __attribute__((ext_vector_type(4))) float f32x4;
typedef unsigned short ushort_t;

// async global->LDS, 16B per lane; LDS dest = wave-uniform base + lane*16
__device__ __forceinline__ void gload_lds16(const ushort_t* g, ushort_t* l){
  __builtin_amdgcn_global_load_lds(
      (const __attribute__((address_space(1))) void*)g,
      (__attribute__((address_space(3))) void*)l, 16, 0, 0);
}

// --- Kernel 1: L2-normalize rows, emit fp16, chunk-XOR-swizzled layout ------
// Within each row's 64B k-group (32 f16), 16B chunk c stored at c ^ ((row>>1)&3).
// k_gemm stages linearly (global_load_lds) and applies the same XOR on ds_read
// (involution, rule #21) -> conflict-free (verified 8.5M -> 0 in round 3).
__global__ __launch_bounds__(256) void k_normalize(const float* __restrict__ x,
                                                   ushort_t* __restrict__ q){
  const int row  = blockIdx.x * 4 + (threadIdx.x >> 6);
  const int lane = threadIdx.x & 63;
  const float* xr = x + (size_t)row * DIM + lane * 8;
  float4 a = *(const float4*)xr;
  float4 b = *(const float4*)(xr + 4);
  float s = a.x*a.x + a.y*a.y + a.z*a.z + a.w*a.w
          + b.x*b.x + b.y*b.y + b.z*b.z + b.w*b.w;
  #pragma unroll
  for (int m = 1; m < 64; m <<= 1) s += __shfl_xor(s, m);
  const float inv = 1.0f / fmaxf(sqrtf(s), 1e-12f);
  float f[8] = {a.x, a.y, a.z, a.w, b.x, b.y, b.z, b.w};
  half8 h;
  #pragma unroll
  for (int e = 0; e < 8; e++) h[e] = (_Float16)(f[e] * inv);
  const int grp = lane >> 2;
  const int ch  = lane & 3;
  const int sw  = (row >> 1) & 3;
  size_t off = (size_t)row * DIM + grp * 32 + (size_t)(ch ^ sw) * 8;
  *(half8*)(q + off) = h;
}

// --- one BK=32 k-step: 12 swizzled ds_read_b128 + 32 MFMA (fp16) ------------
__device__ __forceinline__ void compute_step(const ushort_t* sA, const ushort_t* sB,
                                             const int ra[8], const int rb[4],
                                             f32x4 (&acc)[8][4]){
  half8 av[8], bv[4];
  #pragma unroll
  for (int m = 0; m < 8; m++) av[m] = *(const half8*)(sA + ra[m]);
  #pragma unroll
  for (int n = 0; n < 4; n++) bv[n] = *(const half8*)(sB + rb[n]);
  #pragma unroll
  for (int m = 0; m < 8; m++)
    #pragma unroll
    for (int n = 0; n < 4; n++)
      acc[m][n] = __builtin_amdgcn_mfma_f32_16x16x32_f16(av[m], bv[n], acc[m][n], 0, 0, 0);
}

// --- Kernel 2: rect-triangular tiled q*q^T, fused exp/mask/reduce -----------
// Block = 256 rows (superblock I) x 128 cols (tile J), J >= 2I.
// 4 waves 2x2, wave tile 128x64 = 8x4 frags. 2-phase dbuf, 48KB LDS,
// 2 blocks/CU. Mirror (col-sum) path only when J >= 2I+2; the two
// J in {2I, 2I+1} tiles give full ordered coverage of the diagonal
// superblock -> row-sums only there. Slots: row path J*2+wc in [4I,128),
// mirror path I*4+wr*2+h in [0,4I) -> complete, write-once, deterministic.
__global__ __launch_bounds__(256, 2) void k_gemm(const ushort_t* __restrict__ q,
                                                 const int* __restrict__ labels,
                                                 float* __restrict__ ppos,
                                                 float* __restrict__ ptot){
  // XCD swizzle (1056 = 8 x 132): consecutive logical ids share an XCD
  const int bid = (blockIdx.x % 8) * 132 + blockIdx.x / 8;
  // decode: start(I) = I*(65-I); J = 2I + (bid - start(I))
  int I = (int)((65.0f - sqrtf(4225.0f - 4.0f * (float)bid)) * 0.5f);
  while ((I + 1) * (64 - I) <= bid) I++;
  while (I * (65 - I) > bid) I--;
  const int J = 2 * I + (bid - I * (65 - I));
  const bool mirror = (J >= 2 * I + 2);
  const int rowbase = I * 256, colbase = J * 128;

  __shared__ ushort_t sA[2][256 * 32];   // 2 x 16 KB
  __shared__ ushort_t sB[2][128 * 32];   // 2 x 8 KB
  __shared__ int labI[256], labJ[128];
  labI[threadIdx.x] = labels[rowbase + threadIdx.x];
  if (threadIdx.x < 128) labJ[threadIdx.x] = labels[colbase + threadIdx.x];

  const int t    = threadIdx.x;
  const int lane = t & 63;
  const int w    = t >> 6;
  const int wr   = w >> 1, wc = w & 1;
  const int lrow = lane & 15;
  const int g    = lane >> 4;

  // staging: thread t, shot s covers LDS bytes s*4096 + t*16
  // -> row s*64 + t/4, 16B chunk (t&3) of the 64B k-group (linear; data
  //    in global memory is already chunk-swizzled by k_normalize)
  const size_t gA = (size_t)(rowbase + (t >> 2)) * DIM + (t & 3) * 8;
  const size_t gB = (size_t)(colbase + (t >> 2)) * DIM + (t & 3) * 8;
  const int dW = w * 512;   // wave-uniform LDS elem base per shot half

#define STAGE(BUF, KK) do {                                          \
    gload_lds16(q + gA +             (KK), sA[BUF] + dW);            \
    gload_lds16(q + gA +  64 * DIM + (KK), sA[BUF] + dW + 2048);     \
    gload_lds16(q + gA + 128 * DIM + (KK), sA[BUF] + dW + 4096);     \
    gload_lds16(q + gA + 192 * DIM + (KK), sA[BUF] + dW + 6144);     \
    gload_lds16(q + gB +             (KK), sB[BUF] + dW);            \
    gload_lds16(q + gB +  64 * DIM + (KK), sB[BUF] + dW + 2048);     \
  } while (0)

  // swizzled fragment read offsets (elems)
  const int gs = (g ^ ((lrow >> 1) & 3)) * 8;
  int ra[8], rb[4];
  #pragma unroll
  for (int m = 0; m < 8; m++) ra[m] = (wr * 128 + m * 16 + lrow) * 32 + gs;
  #pragma unroll
  for (int n = 0; n < 4; n++) rb[n] = (wc * 64 + n * 16 + lrow) * 32 + gs;

  f32x4 acc[8][4];
  #pragma unroll
  for (int m = 0; m < 8; m++)
    #pragma unroll
    for (int n = 0; n < 4; n++)
      acc[m][n] = (f32x4){0.f, 0.f, 0.f, 0.f};

  STAGE(0, 0);
  __syncthreads();

  for (int it = 0; it < 8; it++){
    const int k1 = it * 64;
    STAGE(1, k1 + 32);                       // prefetch odd tile
    compute_step(sA[0], sB[0], ra, rb, acc);
    __syncthreads();
    if (it < 7) STAGE(0, k1 + 64);           // prefetch even tile
    compute_step(sA[1], sB[1], ra, rb, acc);
    __syncthreads();
  }
#undef STAGE

  const int i0 = rowbase + wr * 128;
  const int j0 = colbase + wc * 64;

  int li_[8][4], lj_[4];
  #pragma unroll
  for (int m = 0; m < 8; m++)
    #pragma unroll
    for (int e = 0; e < 4; e++)
      li_[m][e] = labI[wr * 128 + m * 16 + g * 4 + e];
  #pragma unroll
  for (int n = 0; n < 4; n++)
    lj_[n] = labJ[wc * 64 + n * 16 + lrow];

  // exp + diag mask, in place
  const float invT = 14.285714285714286f;  // 1/0.07
  #pragma unroll
  for (int m = 0; m < 8; m++)
    #pragma unroll
    for (int n = 0; n < 4; n++)
      #pragma unroll
      for (int e = 0; e < 4; e++){
        int i = i0 + m * 16 + g * 4 + e;
        int j = j0 + n * 16 + lrow;
        acc[m][n][e] = (i == j) ? 0.0f : __expf(acc[m][n][e] * invT);
      }

  // row sums -> slot J*2 + wc
  {
    float* pp = ppos + (size_t)(J * 2 + wc) * BATCH;
    float* pt = ptot + (size_t)(J * 2 + wc) * BATCH;
    #pragma unroll
    for (int m = 0; m < 8; m++){
      float tr[4] = {0, 0, 0, 0}, pr[4] = {0, 0, 0, 0};
      #pragma unroll
      for (int n = 0; n < 4; n++){
        int lj = lj_[n];
        #pragma unroll
        for (int e = 0; e < 4; e++){
          float v = acc[m][n][e];
          tr[e] += v;
          pr[e] += (li_[m][e] == lj) ? v : 0.0f;
        }
      }
      #pragma unroll
      for (int s = 1; s < 16; s <<= 1){
        #pragma unroll
        for (int e = 0; e < 4; e++){
          tr[e] += __shfl_xor(tr[e], s);
          pr[e] += __shfl_xor(pr[e], s);
        }
      }
      if (lrow == 0){
        int ib = i0 + m * 16 + g * 4;
        #pragma unroll
        for (int e = 0; e < 4; e++){
          pt[ib + e] = tr[e];
          pp[ib + e] = pr[e];
        }
      }
    }
  }

  // col sums via symmetry -> slots I*4 + wr*2 + h (h = m-half)
  if (mirror){
    #pragma unroll
    for (int h = 0; h < 2; h++){
      float* pp = ppos + (size_t)(I * 4 + wr * 2 + h) * BATCH;
      float* pt = ptot + (size_t)(I * 4 + wr * 2 + h) * BATCH;
      #pragma unroll
      for (int n = 0; n < 4; n++){
        float ts = 0.f, ps = 0.f;
        int lj = lj_[n];
        #pragma unroll
        for (int m = h * 4; m < h * 4 + 4; m++)
          #pragma unroll
          for (int e = 0; e < 4; e++){
            float v = acc[m][n][e];
            ts += v;
            ps += (li_[m][e] == lj) ? v : 0.0f;
          }
        ts += __shfl_xor(ts, 16); ps += __shfl_xor(ps, 16);
        ts += __shfl_xor(ts, 32); ps += __shfl_xor(ps, 32);
        if (lane < 16){
          int j = j0 + n * 16 + lane;
          pt[j] = ts;
          pp[j] = ps;
        }
      }
    }
  }
}

// --- Kernel 3: per-row loss, per-block partial sum --------------------------
__global__ __launch_bounds__(256) void k_rowloss(const float* __restrict__ ppos,
                                                 const float* __restrict__ ptot,
                                                 float* __restrict__ bsum){
  const int i = blockIdx.x * 256 + threadIdx.x;
  float p = 0.f, t = 0.f;
  for (int c = 0; c < 128; c++){
    p += ppos[(size_t)c * BATCH + i];
    t += ptot[(size_t)c * BATCH + i];
  }
  float loss = -logf(p / (t + 1e-8f));
  float v = loss;
  #pragma unroll
  for (int s = 1; s < 64; s <<= 1) v += __shfl_xor(v, s);
  __shared__ float ws4[4];
  if ((threadIdx.x & 63) == 0) ws4[threadIdx.x >> 6] = v;
  __syncthreads();
  if (threadIdx.x == 0) bsum[blockIdx.x] = ws4[0] + ws4[1] + ws4[2] + ws4[3];
}

// --- Kernel 4: final mean ---------------------------------------------------
__global__ __launch_bounds__(64) void k_final(const float* __restrict__ bsum,
                                              float* __restrict__ out){
  float v = (threadIdx.x < 32) ? bsum[threadIdx.x] : 0.f;
  #pragma unroll
  for (int s = 1; s < 64; s <<= 1) v += __shfl_xor(v, s);
  if (threadIdx.x == 0) out[0] = v * (1.0f / 8192.0f);
}

extern "C" void kernel_launch(void* const* d_in, const int* in_sizes, int n_in,
                              void* d_out, int out_size, void* d_ws, size_t ws_size,
                              hipStream_t stream){
  const float* x      = (const float*)d_in[0];
  const int*   labels = (const int*)d_in[1];
  float*       out    = (float*)d_out;

  char* ws = (char*)d_ws;
  ushort_t* q  = (ushort_t*)ws;                      //  8,388,608 B (8192x512 f16)
  float* ppos  = (float*)(ws + 8388608);             //  4,194,304 B (128 x 8192 f32)
  float* ptot  = (float*)(ws + 8388608 + 4194304);   //  4,194,304 B
  float* bsum  = (float*)(ws + 8388608 + 8388608);   //        128 B

  k_normalize<<<BATCH / 4, 256, 0, stream>>>(x, q);
  k_gemm<<<NBLK, 256, 0, stream>>>(q, labels, ppos, ptot);
  k_rowloss<<<BATCH / 256, 256, 0, stream>>>(ppos, ptot, bsum);
  k_final<<<1, 64, 0, stream>>>(bsum, out);
}